// Round 1
// baseline (374.747 us; speedup 1.0000x reference)
//
#include <hip/hip_runtime.h>

#define BATCH 64
#define SEQ   128
#define NLAB  32

// ---------------------------------------------------------------------------
// Kernel 1: per-cell label reduction.
//   pot[b,i,j] = max_l (logits' + 1 - gold_onehot + special_augment)
//   gold[b]   += logits'[b,i,j,label]
//   lenbuf[b]  = count(labels[b,0,:] != -100)
// logits' = logits - logits[...,0:1]
// 8 lanes per cell, each lane loads one float4 (coalesced 16B/lane).
// ---------------------------------------------------------------------------
__global__ __launch_bounds__(256) void pot_gold_kernel(
    const float* __restrict__ logits, const int* __restrict__ labels,
    float* __restrict__ pot, float* __restrict__ gold, int* __restrict__ lenbuf)
{
    const int blk = blockIdx.x;
    const int b = blk >> 7;        // / SEQ
    const int i = blk & (SEQ - 1); // % SEQ
    const int tid = threadIdx.x;

    __shared__ int s_len;
    __shared__ float s_red[4];

    int len = SEQ;
    if (i == 0) {
        if (tid == 0) s_len = 0;
        __syncthreads();
        if (tid < SEQ) {
            int lab = labels[(size_t)b * SEQ * SEQ + tid];
            unsigned long long m = __ballot(lab != -100);
            if ((tid & 63) == 0) atomicAdd(&s_len, __popcll(m));
        }
        __syncthreads();
        len = s_len;
        if (tid == 0) lenbuf[b] = len;
    }

    const int s = tid & 7;        // sub-lane within cell group (0..7)
    const int cell = tid >> 3;    // 0..31 cells per iteration
    float gsum = 0.0f;

    const size_t row_base = (size_t)(b * SEQ + i) * SEQ;

    for (int t = 0; t < 4; ++t) {
        const int j = t * 32 + cell;
        const float4 v = reinterpret_cast<const float4*>(
            logits + ((row_base + j) << 5))[s];
        const int lab = labels[row_base + j];
        const int lab_eff = lab < 0 ? 0 : lab;

        const float l0 = __shfl(v.x, 0, 8);   // logits[...,0] of this cell
        float rr[4] = { v.x - l0, v.y - l0, v.z - l0, v.w - l0 };

        // gold contribution: logits'[label]
        const float cand = rr[lab_eff & 3];
        const float goldc = __shfl(cand, lab_eff >> 2, 8);

        // cost-augmented max over labels
        const bool special = (i == 0) && (j == len - 1);
        const int lbase = s << 2;
        float m = -3.0e38f;
        #pragma unroll
        for (int c = 0; c < 4; ++c) {
            const int l = lbase + c;
            float tv = rr[c] + 1.0f - (l == lab_eff ? 1.0f : 0.0f);
            if (special && l == 0) tv -= 1.0e9f;
            m = fmaxf(m, tv);
        }
        #pragma unroll
        for (int d = 4; d > 0; d >>= 1)
            m = fmaxf(m, __shfl_down(m, d, 8));

        if (s == 0) {
            pot[row_base + j] = m;
            gsum += goldc;
        }
    }

    // block reduction of gold partials (non-zero only on s==0 lanes)
    #pragma unroll
    for (int d = 32; d > 0; d >>= 1) gsum += __shfl_down(gsum, d, 64);
    const int wave = tid >> 6;
    if ((tid & 63) == 0) s_red[wave] = gsum;
    __syncthreads();
    if (tid == 0) {
        atomicAdd(&gold[b], s_red[0] + s_red[1] + s_red[2] + s_red[3]);
    }
}

// ---------------------------------------------------------------------------
// Kernel 2: max-plus CKY inside pass, one block per batch element.
//   A[i][w]  = best score of span starting at i, width w
//   Bt[j][w] = best score of span ending  at j, width w
//   A[i][w] = pot[i][i+w] + max_{k<w} A[i][k] + Bt[i+w][w-1-k]
// LDS: 2 * 128*129*4 = 132 KB (fits in 160 KB; +1 pad -> <=2-way bank alias).
// Per width-step, entries are split over power-of-2 lane sub-groups.
// ---------------------------------------------------------------------------
__global__ __launch_bounds__(256) void cky_kernel(
    const float* __restrict__ pot, const float* __restrict__ gold,
    const int* __restrict__ lenbuf, float* __restrict__ out)
{
    const int b = blockIdx.x;
    const int tid = threadIdx.x;
    __shared__ float A[SEQ][SEQ + 1];
    __shared__ float Bt[SEQ][SEQ + 1];
    const float* p = pot + (size_t)b * SEQ * SEQ;

    if (tid < SEQ) {
        const float term = p[tid * SEQ + tid];
        A[tid][0] = term;
        Bt[tid][0] = term;
    }
    __syncthreads();

    for (int w = 1; w < SEQ; ++w) {
        const int entries = SEQ - w;
        int tpe = 2; // threads per entry (pow2, <=64, entries*tpe <= 256)
        while (tpe < 64 && entries * (tpe << 1) <= 256) tpe <<= 1;
        const int lt = 31 - __clz(tpe);
        const int group = tid >> lt;
        const int s = tid & (tpe - 1);
        if (group < entries) {
            const int i = group;
            const int j = i + w;
            float partial = -3.0e38f;
            for (int k = s; k < w; k += tpe)
                partial = fmaxf(partial, A[i][k] + Bt[j][w - 1 - k]);
            for (int d = tpe >> 1; d > 0; d >>= 1)
                partial = fmaxf(partial, __shfl_down(partial, d, tpe));
            if (s == 0) {
                const float val = partial + p[i * SEQ + j];
                A[i][w] = val;
                Bt[j][w] = val;
            }
        }
        __syncthreads();
    }

    if (tid == 0) {
        const int len = lenbuf[b];
        const float pred = A[0][len - 1];
        float margin = pred - gold[b];
        margin = margin > 0.0f ? margin : 0.0f;
        atomicAdd(out, margin * (1.0f / (float)BATCH));
    }
}

extern "C" void kernel_launch(void* const* d_in, const int* in_sizes, int n_in,
                              void* d_out, int out_size, void* d_ws, size_t ws_size,
                              hipStream_t stream) {
    const float* logits = (const float*)d_in[0];
    const int* labels = (const int*)d_in[1];
    float* out = (float*)d_out;

    float* pot = (float*)d_ws;                          // B*N*N floats = 4 MB
    float* gold = pot + (size_t)BATCH * SEQ * SEQ;      // B floats
    int* lenbuf = (int*)(gold + BATCH);                 // B ints

    hipMemsetAsync(out, 0, sizeof(float), stream);
    hipMemsetAsync(gold, 0, BATCH * sizeof(float), stream);

    pot_gold_kernel<<<BATCH * SEQ, 256, 0, stream>>>(logits, labels, pot, gold, lenbuf);
    cky_kernel<<<BATCH, 256, 0, stream>>>(pot, gold, lenbuf, out);
}